// Round 24
// baseline (174.010 us; speedup 1.0000x reference)
//
#include <hip/hip_runtime.h>
#include <cstdint>
#include <cstddef>

// Shapes (fixed by the problem)
//  B=4 S=2048 D=1152 H=16 KVH=4 HD=64 SW=1792
// d_out layout (fp32): out[4*2048*1152] | new_ck[4*1792*4*64] | new_cv[4*1792*4*64]

typedef unsigned short u16;
typedef unsigned int   u32;
typedef __attribute__((ext_vector_type(8))) short bf16x8;   // 8 bf16 (4 VGPRs)
typedef __attribute__((ext_vector_type(4))) float f32x4;

#define AS1(p) ((const __attribute__((address_space(1))) void*)(p))
#define AS3(p) ((__attribute__((address_space(3))) void*)(p))

__device__ __forceinline__ u16 f2bf(float f) {
  u32 u = __float_as_uint(f);
  u += 0x7fffu + ((u >> 16) & 1u);      // RNE
  return (u16)(u >> 16);
}
__device__ __forceinline__ float bf2f(u32 x) { return __uint_as_float(x << 16); }
__device__ __forceinline__ f32x4 mfma16(bf16x8 a, bf16x8 b, f32x4 c) {
  return __builtin_amdgcn_mfma_f32_16x16x32_bf16(a, b, c, 0, 0, 0);
}
__device__ __forceinline__ u32 cvtpk_bf16(float lo, float hi) {
  u32 r;
  asm("v_cvt_pk_bf16_f32 %0, %1, %2" : "=v"(r) : "v"(lo), "v"(hi));
  return r;
}

// ---------------- fp32 -> bf16 convert, QKV WEIGHTS ONLY --------------------
//   wq: [0,      294912) float4
//   wk: [294912, 368640)
//   wv: [368640, 442368)
__global__ __launch_bounds__(256) void cvt3_kernel(const float* __restrict__ wq,
                                                   const float* __restrict__ wk,
                                                   const float* __restrict__ wv,
                                                   u16* __restrict__ wqkvb) {
  int i = blockIdx.x * 256 + threadIdx.x;   // float4 index, total 442368
  const float* in; u16* out; int off;
  if (i < 294912)       { in = wq; out = wqkvb;               off = i; }
  else if (i < 368640)  { in = wk; out = wqkvb + 1024 * 1152; off = i - 294912; }
  else                  { in = wv; out = wqkvb + 1280 * 1152; off = i - 368640; }
  float4 v = ((const float4*)in)[off];
  uint2 o;
  o.x = (u32)f2bf(v.x) | ((u32)f2bf(v.y) << 16);
  o.y = (u32)f2bf(v.z) | ((u32)f2bf(v.w) << 16);
  ((uint2*)out)[off] = o;
}

// ---------------- bf16 NT-GEMM: C[m,n] = sum_k A[m,k]*B[n,k] ----------------
// 1-D grid of 64*NT blocks; XCD-local mapping (verified R12: -11.5us).
// A_FP32 path: A fp32 reg-staged with T14 issue-early prefetch (verified R23).
// FUSE_KROPE (QKV GEMM only): blocks whose n-tile lies in k-cols [1024,1280)
// apply RoPE in the epilogue (lane-pair shfl, verified R20) and scatter the
// fp32 k-cache; qkv then holds roped k directly.
template<int BF16_OUT, int A_FP32>
__global__ __launch_bounds__(256) void gemm_bt(const void* __restrict__ Araw,
                                               const u16* __restrict__ B,
                                               void* __restrict__ C,
                                               int M, int N, int K, int NT,
                                               float* __restrict__ nck,
                                               const float* __restrict__ cosT,
                                               const float* __restrict__ sinT) {
  __shared__ u16 As[128][64];
  __shared__ u16 Bs[128][64];
  const int tid  = threadIdx.x;
  const int w    = tid >> 6, lane = tid & 63;
  const int l15  = lane & 15, hi4 = lane >> 4;
  const int lid  = blockIdx.x;
  const int k_   = lid >> 3;
  const int by   = (lid & 7) + 8 * (k_ / NT);
  const int bx   = k_ % NT;
  const int m0   = by * 128, n0 = bx * 128;
  const int wr   = w >> 1, wc = w & 1;

  const int srow = lane >> 3;
  const int slot = lane & 7;
  const int scol = (slot ^ srow) << 3;
  const u16*   Ab  = (const u16*)Araw + (size_t)(m0 + w * 32 + srow) * K + scol;
  const float* Af  = (const float*)Araw + (size_t)(m0 + w * 32 + srow) * K + slot * 8;
  const u16*   Bb  = B + (size_t)(n0 + w * 32 + srow) * K + scol;
  u16* AsDst = &As[w * 32][0];
  u16* BsDst = &Bs[w * 32][0];

  const int swz = (l15 & 7) << 4;
  const int c0  = (((hi4 * 16)      ^ swz) >> 1);
  const int c1  = (((64 + hi4 * 16) ^ swz) >> 1);
  const u16* aRd = &As[wr * 64 + l15][0];
  const u16* bRd = &Bs[wc * 64 + l15][0];

  f32x4 acc[4][4] = {};

  if (A_FP32) {
    // T14 issue-early reg-staged A; raw barriers with counted vmcnt.
    float4 pfa[4][2];
#pragma unroll
    for (int q = 0; q < 4; q++) {
      const float* src = Af + (size_t)q * 8 * K;
      pfa[q][0] = *(const float4*)src;
      pfa[q][1] = *(const float4*)(src + 4);
    }
    for (int kk = 0; kk < K; kk += 64) {
#pragma unroll
      for (int q = 0; q < 4; q++) {
        __builtin_amdgcn_global_load_lds(AS1(Bb + kk + (size_t)q * 8 * K),
                                         AS3(BsDst + q * 8 * 64), 16, 0, 0);
        u32 d[4];
        d[0] = cvtpk_bf16(pfa[q][0].x, pfa[q][0].y);
        d[1] = cvtpk_bf16(pfa[q][0].z, pfa[q][0].w);
        d[2] = cvtpk_bf16(pfa[q][1].x, pfa[q][1].y);
        d[3] = cvtpk_bf16(pfa[q][1].z, pfa[q][1].w);
        *(uint4*)&As[w * 32 + q * 8 + srow][scol] = *(uint4*)&d[0];
      }
      __builtin_amdgcn_sched_barrier(0);    // pin: B gloads precede A prefetch
      if (kk + 64 < K) {
#pragma unroll
        for (int q = 0; q < 4; q++) {
          const float* src = Af + kk + 64 + (size_t)q * 8 * K;
          pfa[q][0] = *(const float4*)src;
          pfa[q][1] = *(const float4*)(src + 4);
        }
      }
      __builtin_amdgcn_sched_barrier(0);    // pin: prefetch issued before wait
      if (kk + 64 < K) asm volatile("s_waitcnt vmcnt(8) lgkmcnt(0)" ::: "memory");
      else             asm volatile("s_waitcnt vmcnt(0) lgkmcnt(0)" ::: "memory");
      __builtin_amdgcn_s_barrier();
      __builtin_amdgcn_sched_barrier(0);
#pragma unroll
      for (int ks = 0; ks < 2; ks++) {
        const int cc = ks ? c1 : c0;
        bf16x8 af[4], bfr[4];
#pragma unroll
        for (int t = 0; t < 4; t++) af[t]  = *(const bf16x8*)(aRd + t * 16 * 64 + cc);
#pragma unroll
        for (int t = 0; t < 4; t++) bfr[t] = *(const bf16x8*)(bRd + t * 16 * 64 + cc);
#pragma unroll
        for (int mi = 0; mi < 4; mi++)
#pragma unroll
          for (int ni = 0; ni < 4; ni++)
            acc[mi][ni] = mfma16(af[mi], bfr[ni], acc[mi][ni]);
      }
      __builtin_amdgcn_s_barrier();
      __builtin_amdgcn_sched_barrier(0);
    }
  } else {
    for (int kk = 0; kk < K; kk += 64) {
#pragma unroll
      for (int q = 0; q < 4; q++) {
        __builtin_amdgcn_global_load_lds(AS1(Ab + kk + (size_t)q * 8 * K),
                                         AS3(AsDst + q * 8 * 64), 16, 0, 0);
        __builtin_amdgcn_global_load_lds(AS1(Bb + kk + (size_t)q * 8 * K),
                                         AS3(BsDst + q * 8 * 64), 16, 0, 0);
      }
      __syncthreads();
#pragma unroll
      for (int ks = 0; ks < 2; ks++) {
        const int cc = ks ? c1 : c0;
        bf16x8 af[4], bfr[4];
#pragma unroll
        for (int t = 0; t < 4; t++) af[t]  = *(const bf16x8*)(aRd + t * 16 * 64 + cc);
#pragma unroll
        for (int t = 0; t < 4; t++) bfr[t] = *(const bf16x8*)(bRd + t * 16 * 64 + cc);
#pragma unroll
        for (int mi = 0; mi < 4; mi++)
#pragma unroll
          for (int ni = 0; ni < 4; ni++)
            acc[mi][ni] = mfma16(af[mi], bfr[ni], acc[mi][ni]);
      }
      __syncthreads();
    }
  }

  // epilogue: k-col tiles (n0 in [1024,1280), QKV GEMM only) rope + cache.
  if (A_FP32 && n0 >= 1024 && n0 < 1280) {
#pragma unroll
    for (int mi = 0; mi < 4; mi++) {
#pragma unroll
      for (int r = 0; r < 4; r++) {
        int row = m0 + wr * 64 + mi * 16 + hi4 * 4 + r;
        size_t base = (size_t)row * N + n0 + wc * 64 + l15;
        const int s = row & 2047, bb = row >> 11;
#pragma unroll
        for (int ni = 0; ni < 4; ni++) {
          float v = acc[mi][ni][r];
          float part = __shfl_xor(v, 1);     // col partner c^1 sits in lane^1
          const int cg = n0 + wc * 64 + ni * 16 + l15;
          const int hh = (cg & 63) >> 1;
          float cs = cosT[s * 32 + hh], sn = sinT[s * 32 + hh];
          float sgn = (l15 & 1) ? sn : -sn;
          float ov = v * cs + part * sgn;    // even: v*c - p*s ; odd: p*s + v*c
          ((u16*)C)[base + ni * 16] = f2bf(ov);
          if (s >= 256) {
            int pc = (s < 1792) ? s : s - 1792;
            nck[(((size_t)bb * 1792 + pc) * 4 + ((cg - 1024) >> 6)) * 64 + (cg & 63)] = ov;
          }
        }
      }
    }
    return;
  }

#pragma unroll
  for (int mi = 0; mi < 4; mi++) {
#pragma unroll
    for (int r = 0; r < 4; r++) {
      int row = m0 + wr * 64 + mi * 16 + hi4 * 4 + r;
      size_t base = (size_t)row * N + n0 + wc * 64 + l15;
#pragma unroll
      for (int ni = 0; ni < 4; ni++) {
        float v = acc[mi][ni][r];
        if (BF16_OUT) ((u16*)C)[base + ni * 16] = f2bf(v);
        else          ((float*)C)[base + ni * 16] = v;
      }
    }
  }
}

// ---------------- V path (cv + permuted vT) + wo convert --------------------
// blocks [0, 512): v path — new_cv fp32 + vT transpose (virtual-k permuted:
//   position p holds key pi(p) = (p&~31) + (e<4 ? 4g+e : 16+4g+e-4))
// blocks [512, 1664): wo fp32->bf16 (needed only by the out GEMM)
__global__ __launch_bounds__(256) void ropev_kernel(const u16* __restrict__ buf,
                                                    u16* __restrict__ vT,
                                                    float* __restrict__ ncv,
                                                    const float* __restrict__ wo,
                                                    u16* __restrict__ wob) {
  __shared__ u16 tile[64][65];
  if (blockIdx.x < 512) {
    int bi = blockIdx.x;                        // 0..511
    int s0 = (bi & 31) * 64, kvh = (bi >> 5) & 3, b = bi >> 7;
    int t = threadIdx.x;
    int r = t >> 2, cc = (t & 3) * 16;
    const u16* src = buf + (size_t)(b * 2048 + s0 + r) * 1536 + 1280 + kvh * 64 + cc;
    uint4 v0 = *(const uint4*)src;
    uint4 v1 = *(const uint4*)(src + 8);
    u16 vals[16];
    *(uint4*)&vals[0] = v0;
    *(uint4*)&vals[8] = v1;
    int s = s0 + r;
    if (s >= 256) {
      int pc = (s < 1792) ? s : s - 1792;
      float* dst = ncv + (size_t)(b * 1792 + pc) * 256 + kvh * 64 + cc;
#pragma unroll
      for (int i = 0; i < 16; i += 4) {
        float4 f = make_float4(bf2f(vals[i]), bf2f(vals[i + 1]),
                               bf2f(vals[i + 2]), bf2f(vals[i + 3]));
        *(float4*)(dst + i) = f;
      }
    }
#pragma unroll
    for (int i = 0; i < 16; i++) tile[cc + i][r] = vals[i];
    __syncthreads();
    u16 ov[16];
#pragma unroll
    for (int i = 0; i < 16; i++) {
      int p = cc + i;                            // vT position (within 64)
      int pg = p & 31, e = pg & 7, g = pg >> 3;
      int key = (p & ~31) + ((e < 4) ? (4 * g + e) : (16 + 4 * g + (e - 4)));
      ov[i] = tile[r][key];                      // store key pi(p) at position p
    }
    u16* dst2 = vT + (size_t)((b * 4 + kvh) * 64 + r) * 2048 + s0 + cc;
    *(uint4*)dst2 = *(uint4*)&ov[0];
    *(uint4*)(dst2 + 8) = *(uint4*)&ov[8];
  } else {
    int i = (blockIdx.x - 512) * 256 + threadIdx.x;    // 0..294911 float4
    float4 v = ((const float4*)wo)[i];
    uint2 o;
    o.x = (u32)f2bf(v.x) | ((u32)f2bf(v.y) << 16);
    o.y = (u32)f2bf(v.z) | ((u32)f2bf(v.w) << 16);
    ((uint2*)wob)[i] = o;
  }
}

// ---------------- Flash attention, sliding-window causal, GQA ----------------
// EXACT R21 structure (best: 60.2us): R17 pipeline + fused Q-RoPE prologue
// (scale 0.125*log2e folded into per-lane cos/sin).
__global__ __launch_bounds__(256) void attn_kernel(const u16* __restrict__ qkv,
                                                   const u16* __restrict__ vT,
                                                   u16* __restrict__ attnb,
                                                   const float* __restrict__ cosT,
                                                   const float* __restrict__ sinT) {
  __shared__ __align__(16) u16 Kbuf[2][64][64];   // [buf][s][hd]   slot ^= (s&7)
  __shared__ __align__(16) u16 Vbuf[2][64][64];   // [buf][hd][pk]  slot ^= (hd&7)
  const int tid = threadIdx.x;
  const int w = tid >> 6, lane = tid & 63;
  const int l15 = lane & 15, hi4 = lane >> 4;

  // bijective XCD swizzle over 1024 blocks: 128 consecutive wgids per XCD
  const int lid  = blockIdx.x;
  const int wgid = (lid & 7) * 128 + (lid >> 3);
  const int gx   = wgid & 63;
  const int rr   = wgid >> 6;
  const int kvh  = rr & 3, b = rr >> 2;
  const int i0   = 32 * (63 - gx);                // heavy-first
  const int h    = kvh * 4 + w;

  const u16* qbase = qkv + (size_t)(b * 2048) * 1536 + h * 64;
  const u16* kbase = qkv + (size_t)(b * 2048) * 1536 + 1024 + kvh * 64;
  const u16* vbase = vT + (size_t)((b * 4 + kvh) * 64) * 2048;

  // Q fragments + fused RoPE (scale folded into cos/sin)
  const float qs = 0.18033688011112042f;          // 0.125 * log2(e)
  bf16x8 qa[2][2];
  {
    const u16* qp = qbase + (size_t)(i0 + l15) * 1536 + hi4 * 8;
#pragma unroll
    for (int m = 0; m < 2; m++) {
      const int s = i0 + m * 16 + l15;
#pragma unroll
      for (int ki = 0; ki < 2; ki++) {
        bf16x8 qv = *(const bf16x8*)(qp + m * 16 * 1536 + ki * 32);
        const int hh0 = ki * 16 + hi4 * 4;
        float4 cs = *(const float4*)(cosT + s * 32 + hh0);
        float4 sn = *(const float4*)(sinT + s * 32 + hh0);
        cs.x *= qs; cs.y *= qs; cs.z *= qs; cs.w *= qs;
        sn.x *= qs; sn.y *= qs; sn.z *= qs; sn.w *= qs;
        u32 wds[4];
        {
          float a = bf2f((u16)qv[0]), bb2 = bf2f((u16)qv[1]);
          wds[0] = cvtpk_bf16(a * cs.x - bb2 * sn.x, a * sn.x + bb2 * cs.x);
        }
        {
          float a = bf2f((u16)qv[2]), bb2 = bf2f((u16)qv[3]);
          wds[1] = cvtpk_bf16(a * cs.y - bb2 * sn.y, a * sn.y + bb2 * cs.y);
        }
        {
          float a = bf2f((u16)qv[4]), bb2 = bf2f((u16)qv[5]);
          wds[2] = cvtpk_bf16(a * cs.z - bb2 * sn.z, a * sn.z + bb2 * cs.z);
        }
        {
          float a = bf2f((u16)qv[6]), bb2 = bf2f((u16)qv[7]);
          wds[3] = cvtpk_bf16(a * cs.w - bb2 * sn.w, a * sn.w + bb2 * cs.w);
        }
        qa[m][ki] = *(const bf16x8*)&wds[0];
      }
    }
  }

  bf16x8 ones;
#pragma unroll
  for (int i = 0; i < 8; i++) ones[i] = (short)0x3F80;

  f32x4 o[2][4] = {};
  f32x4 ol[2] = {};

  const int srow = lane >> 3;                 // 0..7
  const int ssl  = (lane & 7) ^ srow;         // pre-swizzled source 16B slot

#define STAGE(J0, BS)                                                                     \
  do {                                                                                    \
    _Pragma("unroll")                                                                     \
    for (int q = 0; q < 2; q++) {                                                         \
      const int row = 32 * q + 8 * w + srow;                                              \
      __builtin_amdgcn_global_load_lds(AS1(kbase + (size_t)((J0) + row) * 1536 + ssl * 8),\
                                       AS3(&Kbuf[BS][32 * q + 8 * w][0]), 16, 0, 0);      \
      __builtin_amdgcn_global_load_lds(AS1(vbase + (size_t)row * 2048 + (J0) + ssl * 8),  \
                                       AS3(&Vbuf[BS][32 * q + 8 * w][0]), 16, 0, 0);      \
    }                                                                                     \
  } while (0)

  int jstart = i0 - 1791;
  if (jstart < 0) jstart = 0;
  jstart &= ~63;
  const int jend = i0 + 32;
  const int ntiles = (jend - jstart + 63) >> 6;

  STAGE(jstart, 0);
  if (ntiles > 1) STAGE(jstart + 64, 1);

  for (int t = 0; t < ntiles; t++) {
    const int j0 = jstart + 64 * t;
    if (t + 1 < ntiles) asm volatile("s_waitcnt vmcnt(4)" ::: "memory");
    else                asm volatile("s_waitcnt vmcnt(0)" ::: "memory");
    __builtin_amdgcn_s_barrier();
    __builtin_amdgcn_sched_barrier(0);      // pin: nothing crosses above barrier

    const u16* Kb = &Kbuf[t & 1][0][0];
    const u16* Vb = &Vbuf[t & 1][0][0];

    // K fragments (fence-free; compiler inserts per-use lgkmcnt)
    bf16x8 kf[2][4];
#pragma unroll
    for (int nt = 0; nt < 4; nt++)
#pragma unroll
      for (int ki = 0; ki < 2; ki++)
        kf[ki][nt] = *(const bf16x8*)(Kb + (nt * 16 + l15) * 64 +
                                      (((ki * 4 + hi4) ^ (l15 & 7)) << 3));

    // V fragments: single b128 per (kbp,tt) — vT pre-permuted; conflict-free
    bf16x8 vf[2][4];
#pragma unroll
    for (int tt = 0; tt < 4; tt++) {
      const int row = tt * 16 + l15;
#pragma unroll
      for (int kbp = 0; kbp < 2; kbp++)
        vf[kbp][tt] = *(const bf16x8*)(Vb + row * 64 +
                                       (((kbp * 4 + hi4) ^ (l15 & 7)) << 3));
    }

    __builtin_amdgcn_s_setprio(1);
    const bool fast = (j0 + 63 <= i0) && (i0 + 31 - j0 < 1792);
#pragma unroll
    for (int m = 0; m < 2; m++) {
      __align__(16) u32 pkb[8];                // P dwords: k = 16nt+4*hi4+{0..3}
#pragma unroll
      for (int nt = 0; nt < 4; nt++) {
        f32x4 s = {0.f, 0.f, 0.f, 0.f};
        s = mfma16(kf[0][nt], qa[m][0], s);
        s = mfma16(kf[1][nt], qa[m][1], s);
        float p[4];
        if (fast) {
#pragma unroll
          for (int r = 0; r < 4; r++) p[r] = __builtin_amdgcn_exp2f(s[r]);
        } else {
          const int i = i0 + m * 16 + l15;
#pragma unroll
          for (int r = 0; r < 4; r++) {
            const int j = j0 + nt * 16 + hi4 * 4 + r;
            p[r] = (j <= i && i - j < 1792) ? __builtin_amdgcn_exp2f(s[r]) : 0.f;
          }
        }
        pkb[nt * 2]     = cvtpk_bf16(p[0], p[1]);
        pkb[nt * 2 + 1] = cvtpk_bf16(p[2], p[3]);
      }
      bf16x8 pa0 = *(const bf16x8*)&pkb[0];    // virtual-k keys 0..31  (nt 0,1)
      bf16x8 pa1 = *(const bf16x8*)&pkb[4];    // virtual-k keys 32..63 (nt 2,3)
#pragma unroll
      for (int tt = 0; tt < 4; tt++) {
        o[m][tt] = mfma16(pa0, vf[0][tt], o[m][tt]);
        o[m][tt] = mfma16(pa1, vf[1][tt], o[m][tt]);
      }
      ol[m] = mfma16(pa0, ones, ol[m]);
      ol[m] = mfma16(pa1, ones, ol[m]);
    }
    __builtin_amdgcn_s_setprio(0);

    // all reads of buf[t&1] consumed above -> after this barrier every wave
    // is done with buf[t&1]; STAGE below can overwrite it.
    __builtin_amdgcn_s_barrier();
    __builtin_amdgcn_sched_barrier(0);      // pin: STAGE stays below barrier
    if (t + 2 < ntiles) STAGE(j0 + 128, t & 1);
  }
#undef STAGE

  u16* op = attnb + (size_t)(b * 2048 + i0 + hi4 * 4) * 1024 + h * 64 + l15;
#pragma unroll
  for (int m = 0; m < 2; m++)
#pragma unroll
    for (int r = 0; r < 4; r++) {
      float inv = 1.0f / ol[m][r];
#pragma unroll
      for (int tt = 0; tt < 4; tt++)
        op[(size_t)(m * 16 + r) * 1024 + 16 * tt] = f2bf(o[m][tt][r] * inv);
    }
}

// ---------------- launch ----------------
extern "C" void kernel_launch(void* const* d_in, const int* in_sizes, int n_in,
                              void* d_out, int out_size, void* d_ws, size_t ws_size,
                              hipStream_t stream) {
  const float* x  = (const float*)d_in[0];
  const float* wq = (const float*)d_in[1];
  const float* wk = (const float*)d_in[2];
  const float* wv = (const float*)d_in[3];
  const float* wo = (const float*)d_in[4];
  const float* fc = (const float*)d_in[5];
  const float* fs = (const float*)d_in[6];

  float* out = (float*)d_out;
  float* nck = out + 9437184;      // 4*2048*1152
  float* ncv = nck + 1835008;      // 4*1792*4*64

  char* ws = (char*)d_ws;
  u16* attnb = (u16*)(ws);                    // attn out bf16 [8192][1024]
  u16* wqkvb = (u16*)(ws + 18874368);         // wq|wk|wv bf16 [1536][1152]
  u16* wob   = (u16*)(ws + 22413312);         // wo bf16       [1152][1024]
  u16* qkv   = (u16*)(ws + 24772608);         // qkv bf16      [8192][1536] (k roped)
  u16* vT    = (u16*)(ws + 49938432);         // v^T bf16 (virtual-k permuted)

  cvt3_kernel<<<1728, 256, 0, stream>>>(wq, wk, wv, wqkvb);

  // QKV GEMM: fp32 A reg-staged (T14); k-col tiles rope + cache in epilogue.
  gemm_bt<1, 1><<<768, 256, 0, stream>>>(x, wqkvb, qkv, 8192, 1536, 1152, 12,
                                         nck, fc, fs);

  ropev_kernel<<<1664, 256, 0, stream>>>(qkv, vT, ncv, wo, wob);

  attn_kernel<<<1024, 256, 0, stream>>>(qkv, vT, attnb, fc, fs);

  gemm_bt<0, 0><<<576, 256, 0, stream>>>(attnb, wob, out, 8192, 1152, 1024, 9,
                                         nullptr, nullptr, nullptr);
}

// Round 25
// 149.623 us; speedup vs baseline: 1.1630x; 1.1630x over previous
//
#include <hip/hip_runtime.h>
#include <cstdint>
#include <cstddef>

// Shapes (fixed by the problem)
//  B=4 S=2048 D=1152 H=16 KVH=4 HD=64 SW=1792
// d_out layout (fp32): out[4*2048*1152] | new_ck[4*1792*4*64] | new_cv[4*1792*4*64]

typedef unsigned short u16;
typedef unsigned int   u32;
typedef __attribute__((ext_vector_type(8))) short bf16x8;   // 8 bf16 (4 VGPRs)
typedef __attribute__((ext_vector_type(4))) float f32x4;

#define AS1(p) ((const __attribute__((address_space(1))) void*)(p))
#define AS3(p) ((__attribute__((address_space(3))) void*)(p))

__device__ __forceinline__ u16 f2bf(float f) {
  u32 u = __float_as_uint(f);
  u += 0x7fffu + ((u >> 16) & 1u);      // RNE
  return (u16)(u >> 16);
}
__device__ __forceinline__ float bf2f(u32 x) { return __uint_as_float(x << 16); }
__device__ __forceinline__ f32x4 mfma16(bf16x8 a, bf16x8 b, f32x4 c) {
  return __builtin_amdgcn_mfma_f32_16x16x32_bf16(a, b, c, 0, 0, 0);
}
__device__ __forceinline__ u32 cvtpk_bf16(float lo, float hi) {
  u32 r;
  asm("v_cvt_pk_bf16_f32 %0, %1, %2" : "=v"(r) : "v"(lo), "v"(hi));
  return r;
}

// ---------------- fp32 -> bf16 convert, QKV WEIGHTS ONLY --------------------
//   wq: [0,      294912) float4
//   wk: [294912, 368640)
//   wv: [368640, 442368)
// (wo conversion deferred into ropev_kernel — only needed by the out GEMM)
__global__ __launch_bounds__(256) void cvt3_kernel(const float* __restrict__ wq,
                                                   const float* __restrict__ wk,
                                                   const float* __restrict__ wv,
                                                   u16* __restrict__ wqkvb) {
  int i = blockIdx.x * 256 + threadIdx.x;   // float4 index, total 442368
  const float* in; u16* out; int off;
  if (i < 294912)       { in = wq; out = wqkvb;               off = i; }
  else if (i < 368640)  { in = wk; out = wqkvb + 1024 * 1152; off = i - 294912; }
  else                  { in = wv; out = wqkvb + 1280 * 1152; off = i - 368640; }
  float4 v = ((const float4*)in)[off];
  uint2 o;
  o.x = (u32)f2bf(v.x) | ((u32)f2bf(v.y) << 16);
  o.y = (u32)f2bf(v.z) | ((u32)f2bf(v.w) << 16);
  ((uint2*)out)[off] = o;
}

// ---------------- bf16 NT-GEMM: C[m,n] = sum_k A[m,k]*B[n,k] ----------------
// 1-D grid of 64*NT blocks; XCD-local mapping (verified R12: -11.5us).
// A_FP32 path: A fp32 is reg-staged with T14 issue-early prefetch (next
// K-step's 8 loads issued BEFORE compute; raw barriers + counted
// vmcnt(8) leave them in flight so their latency hides under the MFMAs).
// B always stages via global_load_lds (pre-swizzled source).
template<int BF16_OUT, int A_FP32>
__global__ __launch_bounds__(256) void gemm_bt(const void* __restrict__ Araw,
                                               const u16* __restrict__ B,
                                               void* __restrict__ C,
                                               int M, int N, int K, int NT) {
  __shared__ u16 As[128][64];
  __shared__ u16 Bs[128][64];
  const int tid  = threadIdx.x;
  const int w    = tid >> 6, lane = tid & 63;
  const int l15  = lane & 15, hi4 = lane >> 4;
  const int lid  = blockIdx.x;
  const int k_   = lid >> 3;
  const int by   = (lid & 7) + 8 * (k_ / NT);
  const int bx   = k_ % NT;
  const int m0   = by * 128, n0 = bx * 128;
  const int wr   = w >> 1, wc = w & 1;

  const int srow = lane >> 3;
  const int slot = lane & 7;
  const int scol = (slot ^ srow) << 3;
  const u16*   Ab  = (const u16*)Araw + (size_t)(m0 + w * 32 + srow) * K + scol;
  const float* Af  = (const float*)Araw + (size_t)(m0 + w * 32 + srow) * K + slot * 8;
  const u16*   Bb  = B + (size_t)(n0 + w * 32 + srow) * K + scol;
  u16* AsDst = &As[w * 32][0];
  u16* BsDst = &Bs[w * 32][0];

  const int swz = (l15 & 7) << 4;
  const int c0  = (((hi4 * 16)      ^ swz) >> 1);
  const int c1  = (((64 + hi4 * 16) ^ swz) >> 1);
  const u16* aRd = &As[wr * 64 + l15][0];
  const u16* bRd = &Bs[wc * 64 + l15][0];

  f32x4 acc[4][4] = {};

  if (A_FP32) {
    // T14 issue-early reg-staged A; raw barriers with counted vmcnt.
    float4 pfa[4][2];
#pragma unroll
    for (int q = 0; q < 4; q++) {
      const float* src = Af + (size_t)q * 8 * K;
      pfa[q][0] = *(const float4*)src;
      pfa[q][1] = *(const float4*)(src + 4);
    }
    for (int kk = 0; kk < K; kk += 64) {
      // stage: B via gload_lds (issued first — oldest in vmcnt queue),
      // A from prefetched regs via cvt + ds_write.
#pragma unroll
      for (int q = 0; q < 4; q++) {
        __builtin_amdgcn_global_load_lds(AS1(Bb + kk + (size_t)q * 8 * K),
                                         AS3(BsDst + q * 8 * 64), 16, 0, 0);
        u32 d[4];
        d[0] = cvtpk_bf16(pfa[q][0].x, pfa[q][0].y);
        d[1] = cvtpk_bf16(pfa[q][0].z, pfa[q][0].w);
        d[2] = cvtpk_bf16(pfa[q][1].x, pfa[q][1].y);
        d[3] = cvtpk_bf16(pfa[q][1].z, pfa[q][1].w);
        *(uint4*)&As[w * 32 + q * 8 + srow][scol] = *(uint4*)&d[0];
      }
      __builtin_amdgcn_sched_barrier(0);    // pin: B gloads precede A prefetch
      if (kk + 64 < K) {
#pragma unroll
        for (int q = 0; q < 4; q++) {
          const float* src = Af + kk + 64 + (size_t)q * 8 * K;
          pfa[q][0] = *(const float4*)src;
          pfa[q][1] = *(const float4*)(src + 4);
        }
      }
      __builtin_amdgcn_sched_barrier(0);    // pin: prefetch issued before wait
      // drain: ds_writes (lgkm) + the 4 B gloads (oldest); leave the 8
      // newest (A prefetch, reg-destined) in flight across the barrier.
      if (kk + 64 < K) asm volatile("s_waitcnt vmcnt(8) lgkmcnt(0)" ::: "memory");
      else             asm volatile("s_waitcnt vmcnt(0) lgkmcnt(0)" ::: "memory");
      __builtin_amdgcn_s_barrier();
      __builtin_amdgcn_sched_barrier(0);
#pragma unroll
      for (int ks = 0; ks < 2; ks++) {
        const int cc = ks ? c1 : c0;
        bf16x8 af[4], bfr[4];
#pragma unroll
        for (int t = 0; t < 4; t++) af[t]  = *(const bf16x8*)(aRd + t * 16 * 64 + cc);
#pragma unroll
        for (int t = 0; t < 4; t++) bfr[t] = *(const bf16x8*)(bRd + t * 16 * 64 + cc);
#pragma unroll
        for (int mi = 0; mi < 4; mi++)
#pragma unroll
          for (int ni = 0; ni < 4; ni++)
            acc[mi][ni] = mfma16(af[mi], bfr[ni], acc[mi][ni]);
      }
      __builtin_amdgcn_s_barrier();         // all waves done reading LDS
      __builtin_amdgcn_sched_barrier(0);    // pin: next stage stays below
    }
  } else {
    for (int kk = 0; kk < K; kk += 64) {
#pragma unroll
      for (int q = 0; q < 4; q++) {
        __builtin_amdgcn_global_load_lds(AS1(Ab + kk + (size_t)q * 8 * K),
                                         AS3(AsDst + q * 8 * 64), 16, 0, 0);
        __builtin_amdgcn_global_load_lds(AS1(Bb + kk + (size_t)q * 8 * K),
                                         AS3(BsDst + q * 8 * 64), 16, 0, 0);
      }
      __syncthreads();
#pragma unroll
      for (int ks = 0; ks < 2; ks++) {
        const int cc = ks ? c1 : c0;
        bf16x8 af[4], bfr[4];
#pragma unroll
        for (int t = 0; t < 4; t++) af[t]  = *(const bf16x8*)(aRd + t * 16 * 64 + cc);
#pragma unroll
        for (int t = 0; t < 4; t++) bfr[t] = *(const bf16x8*)(bRd + t * 16 * 64 + cc);
#pragma unroll
        for (int mi = 0; mi < 4; mi++)
#pragma unroll
          for (int ni = 0; ni < 4; ni++)
            acc[mi][ni] = mfma16(af[mi], bfr[ni], acc[mi][ni]);
      }
      __syncthreads();
    }
  }

#pragma unroll
  for (int mi = 0; mi < 4; mi++) {
#pragma unroll
    for (int r = 0; r < 4; r++) {
      int row = m0 + wr * 64 + mi * 16 + hi4 * 4 + r;
      size_t base = (size_t)row * N + n0 + wc * 64 + l15;
#pragma unroll
      for (int ni = 0; ni < 4; ni++) {
        float v = acc[mi][ni][r];
        if (BF16_OUT) ((u16*)C)[base + ni * 16] = f2bf(v);
        else          ((float*)C)[base + ni * 16] = v;
      }
    }
  }
}

// ---------------- RoPE on K (+ k-cache), V (cv + vT), wo convert ------------
// blocks [0, 4096): k-rope on qkv cols 512..639 (u32 pairs) + fp32 k-cache
// blocks [4096, 4608): v path — new_cv fp32 + vT transpose (virtual-k
//   permuted: position p holds key pi(p))
// blocks [4608, 5760): wo fp32->bf16 (needed only by the out GEMM)
__global__ __launch_bounds__(256) void ropev_kernel(u16* __restrict__ buf,
                                                    float* __restrict__ kcache,
                                                    u16* __restrict__ vT,
                                                    float* __restrict__ ncv,
                                                    const float* __restrict__ wo,
                                                    u16* __restrict__ wob,
                                                    const float* __restrict__ cosT,
                                                    const float* __restrict__ sinT) {
  __shared__ u16 tile[64][65];
  if (blockIdx.x < 4096) {
    int idx = blockIdx.x * 256 + threadIdx.x;   // 0..1048575
    int m = idx >> 7, p = idx & 127;
    int s = m & 2047, b = m >> 11;
    int hh = p & 31;
    u32* bp = (u32*)buf + (size_t)m * 768 + 512 + p;
    u32 pk = *bp;
    float a  = bf2f(pk & 0xffffu), bb = bf2f(pk >> 16);
    float c  = cosT[s * 32 + hh],  sn = sinT[s * 32 + hh];
    float o0 = a * c - bb * sn;
    float o1 = a * sn + bb * c;
    *bp = (u32)f2bf(o0) | ((u32)f2bf(o1) << 16);
    if (s >= 256) {
      int pc = (s < 1792) ? s : s - 1792;
      float2* cp = (float2*)(kcache + (size_t)(b * 1792 + pc) * 256 + 2 * p);
      *cp = make_float2(o0, o1);
    }
  } else if (blockIdx.x < 4608) {
    int bi = blockIdx.x - 4096;                 // 0..511
    int s0 = (bi & 31) * 64, kvh = (bi >> 5) & 3, b = bi >> 7;
    int t = threadIdx.x;
    int r = t >> 2, cc = (t & 3) * 16;
    const u16* src = buf + (size_t)(b * 2048 + s0 + r) * 1536 + 1280 + kvh * 64 + cc;
    uint4 v0 = *(const uint4*)src;
    uint4 v1 = *(const uint4*)(src + 8);
    u16 vals[16];
    *(uint4*)&vals[0] = v0;
    *(uint4*)&vals[8] = v1;
    int s = s0 + r;
    if (s >= 256) {
      int pc = (s < 1792) ? s : s - 1792;
      float* dst = ncv + (size_t)(b * 1792 + pc) * 256 + kvh * 64 + cc;
#pragma unroll
      for (int i = 0; i < 16; i += 4) {
        float4 f = make_float4(bf2f(vals[i]), bf2f(vals[i + 1]),
                               bf2f(vals[i + 2]), bf2f(vals[i + 3]));
        *(float4*)(dst + i) = f;
      }
    }
#pragma unroll
    for (int i = 0; i < 16; i++) tile[cc + i][r] = vals[i];
    __syncthreads();
    u16 ov[16];
#pragma unroll
    for (int i = 0; i < 16; i++) {
      int p = cc + i;                            // vT position (within 64)
      int pg = p & 31, e = pg & 7, g = pg >> 3;
      int key = (p & ~31) + ((e < 4) ? (4 * g + e) : (16 + 4 * g + (e - 4)));
      ov[i] = tile[r][key];                      // store key pi(p) at position p
    }
    u16* dst2 = vT + (size_t)((b * 4 + kvh) * 64 + r) * 2048 + s0 + cc;
    *(uint4*)dst2 = *(uint4*)&ov[0];
    *(uint4*)(dst2 + 8) = *(uint4*)&ov[8];
  } else {
    int i = (blockIdx.x - 4608) * 256 + threadIdx.x;   // 0..294911 float4
    float4 v = ((const float4*)wo)[i];
    uint2 o;
    o.x = (u32)f2bf(v.x) | ((u32)f2bf(v.y) << 16);
    o.y = (u32)f2bf(v.z) | ((u32)f2bf(v.w) << 16);
    ((uint2*)wob)[i] = o;
  }
}

// ---------------- Flash attention, sliding-window causal, GQA ----------------
// EXACT R21 structure (best: 60.2us): R17 pipeline + fused Q-RoPE prologue
// (scale 0.125*log2e folded into per-lane cos/sin).
__global__ __launch_bounds__(256) void attn_kernel(const u16* __restrict__ qkv,
                                                   const u16* __restrict__ vT,
                                                   u16* __restrict__ attnb,
                                                   const float* __restrict__ cosT,
                                                   const float* __restrict__ sinT) {
  __shared__ __align__(16) u16 Kbuf[2][64][64];   // [buf][s][hd]   slot ^= (s&7)
  __shared__ __align__(16) u16 Vbuf[2][64][64];   // [buf][hd][pk]  slot ^= (hd&7)
  const int tid = threadIdx.x;
  const int w = tid >> 6, lane = tid & 63;
  const int l15 = lane & 15, hi4 = lane >> 4;

  // bijective XCD swizzle over 1024 blocks: 128 consecutive wgids per XCD
  const int lid  = blockIdx.x;
  const int wgid = (lid & 7) * 128 + (lid >> 3);
  const int gx   = wgid & 63;
  const int rr   = wgid >> 6;
  const int kvh  = rr & 3, b = rr >> 2;
  const int i0   = 32 * (63 - gx);                // heavy-first
  const int h    = kvh * 4 + w;

  const u16* qbase = qkv + (size_t)(b * 2048) * 1536 + h * 64;
  const u16* kbase = qkv + (size_t)(b * 2048) * 1536 + 1024 + kvh * 64;
  const u16* vbase = vT + (size_t)((b * 4 + kvh) * 64) * 2048;

  // Q fragments + fused RoPE (scale folded into cos/sin)
  const float qs = 0.18033688011112042f;          // 0.125 * log2(e)
  bf16x8 qa[2][2];
  {
    const u16* qp = qbase + (size_t)(i0 + l15) * 1536 + hi4 * 8;
#pragma unroll
    for (int m = 0; m < 2; m++) {
      const int s = i0 + m * 16 + l15;
#pragma unroll
      for (int ki = 0; ki < 2; ki++) {
        bf16x8 qv = *(const bf16x8*)(qp + m * 16 * 1536 + ki * 32);
        const int hh0 = ki * 16 + hi4 * 4;
        float4 cs = *(const float4*)(cosT + s * 32 + hh0);
        float4 sn = *(const float4*)(sinT + s * 32 + hh0);
        cs.x *= qs; cs.y *= qs; cs.z *= qs; cs.w *= qs;
        sn.x *= qs; sn.y *= qs; sn.z *= qs; sn.w *= qs;
        u32 wds[4];
        {
          float a = bf2f((u16)qv[0]), bb2 = bf2f((u16)qv[1]);
          wds[0] = cvtpk_bf16(a * cs.x - bb2 * sn.x, a * sn.x + bb2 * cs.x);
        }
        {
          float a = bf2f((u16)qv[2]), bb2 = bf2f((u16)qv[3]);
          wds[1] = cvtpk_bf16(a * cs.y - bb2 * sn.y, a * sn.y + bb2 * cs.y);
        }
        {
          float a = bf2f((u16)qv[4]), bb2 = bf2f((u16)qv[5]);
          wds[2] = cvtpk_bf16(a * cs.z - bb2 * sn.z, a * sn.z + bb2 * cs.z);
        }
        {
          float a = bf2f((u16)qv[6]), bb2 = bf2f((u16)qv[7]);
          wds[3] = cvtpk_bf16(a * cs.w - bb2 * sn.w, a * sn.w + bb2 * cs.w);
        }
        qa[m][ki] = *(const bf16x8*)&wds[0];
      }
    }
  }

  bf16x8 ones;
#pragma unroll
  for (int i = 0; i < 8; i++) ones[i] = (short)0x3F80;

  f32x4 o[2][4] = {};
  f32x4 ol[2] = {};

  const int srow = lane >> 3;                 // 0..7
  const int ssl  = (lane & 7) ^ srow;         // pre-swizzled source 16B slot

#define STAGE(J0, BS)                                                                     \
  do {                                                                                    \
    _Pragma("unroll")                                                                     \
    for (int q = 0; q < 2; q++) {                                                         \
      const int row = 32 * q + 8 * w + srow;                                              \
      __builtin_amdgcn_global_load_lds(AS1(kbase + (size_t)((J0) + row) * 1536 + ssl * 8),\
                                       AS3(&Kbuf[BS][32 * q + 8 * w][0]), 16, 0, 0);      \
      __builtin_amdgcn_global_load_lds(AS1(vbase + (size_t)row * 2048 + (J0) + ssl * 8),  \
                                       AS3(&Vbuf[BS][32 * q + 8 * w][0]), 16, 0, 0);      \
    }                                                                                     \
  } while (0)

  int jstart = i0 - 1791;
  if (jstart < 0) jstart = 0;
  jstart &= ~63;
  const int jend = i0 + 32;
  const int ntiles = (jend - jstart + 63) >> 6;

  STAGE(jstart, 0);
  if (ntiles > 1) STAGE(jstart + 64, 1);

  for (int t = 0; t < ntiles; t++) {
    const int j0 = jstart + 64 * t;
    if (t + 1 < ntiles) asm volatile("s_waitcnt vmcnt(4)" ::: "memory");
    else                asm volatile("s_waitcnt vmcnt(0)" ::: "memory");
    __builtin_amdgcn_s_barrier();
    __builtin_amdgcn_sched_barrier(0);      // pin: nothing crosses above barrier

    const u16* Kb = &Kbuf[t & 1][0][0];
    const u16* Vb = &Vbuf[t & 1][0][0];

    // K fragments (fence-free; compiler inserts per-use lgkmcnt)
    bf16x8 kf[2][4];
#pragma unroll
    for (int nt = 0; nt < 4; nt++)
#pragma unroll
      for (int ki = 0; ki < 2; ki++)
        kf[ki][nt] = *(const bf16x8*)(Kb + (nt * 16 + l15) * 64 +
                                      (((ki * 4 + hi4) ^ (l15 & 7)) << 3));

    // V fragments: single b128 per (kbp,tt) — vT pre-permuted; conflict-free
    bf16x8 vf[2][4];
#pragma unroll
    for (int tt = 0; tt < 4; tt++) {
      const int row = tt * 16 + l15;
#pragma unroll
      for (int kbp = 0; kbp < 2; kbp++)
        vf[kbp][tt] = *(const bf16x8*)(Vb + row * 64 +
                                       (((kbp * 4 + hi4) ^ (l15 & 7)) << 3));
    }

    __builtin_amdgcn_s_setprio(1);
    const bool fast = (j0 + 63 <= i0) && (i0 + 31 - j0 < 1792);
#pragma unroll
    for (int m = 0; m < 2; m++) {
      __align__(16) u32 pkb[8];                // P dwords: k = 16nt+4*hi4+{0..3}
#pragma unroll
      for (int nt = 0; nt < 4; nt++) {
        f32x4 s = {0.f, 0.f, 0.f, 0.f};
        s = mfma16(kf[0][nt], qa[m][0], s);
        s = mfma16(kf[1][nt], qa[m][1], s);
        float p[4];
        if (fast) {
#pragma unroll
          for (int r = 0; r < 4; r++) p[r] = __builtin_amdgcn_exp2f(s[r]);
        } else {
          const int i = i0 + m * 16 + l15;
#pragma unroll
          for (int r = 0; r < 4; r++) {
            const int j = j0 + nt * 16 + hi4 * 4 + r;
            p[r] = (j <= i && i - j < 1792) ? __builtin_amdgcn_exp2f(s[r]) : 0.f;
          }
        }
        pkb[nt * 2]     = cvtpk_bf16(p[0], p[1]);
        pkb[nt * 2 + 1] = cvtpk_bf16(p[2], p[3]);
      }
      bf16x8 pa0 = *(const bf16x8*)&pkb[0];    // virtual-k keys 0..31  (nt 0,1)
      bf16x8 pa1 = *(const bf16x8*)&pkb[4];    // virtual-k keys 32..63 (nt 2,3)
#pragma unroll
      for (int tt = 0; tt < 4; tt++) {
        o[m][tt] = mfma16(pa0, vf[0][tt], o[m][tt]);
        o[m][tt] = mfma16(pa1, vf[1][tt], o[m][tt]);
      }
      ol[m] = mfma16(pa0, ones, ol[m]);
      ol[m] = mfma16(pa1, ones, ol[m]);
    }
    __builtin_amdgcn_s_setprio(0);

    // all reads of buf[t&1] consumed above -> after this barrier every wave
    // is done with buf[t&1]; STAGE below can overwrite it.
    __builtin_amdgcn_s_barrier();
    __builtin_amdgcn_sched_barrier(0);      // pin: STAGE stays below barrier
    if (t + 2 < ntiles) STAGE(j0 + 128, t & 1);
  }
#undef STAGE

  u16* op = attnb + (size_t)(b * 2048 + i0 + hi4 * 4) * 1024 + h * 64 + l15;
#pragma unroll
  for (int m = 0; m < 2; m++)
#pragma unroll
    for (int r = 0; r < 4; r++) {
      float inv = 1.0f / ol[m][r];
#pragma unroll
      for (int tt = 0; tt < 4; tt++)
        op[(size_t)(m * 16 + r) * 1024 + 16 * tt] = f2bf(o[m][tt][r] * inv);
    }
}

// ---------------- launch ----------------
extern "C" void kernel_launch(void* const* d_in, const int* in_sizes, int n_in,
                              void* d_out, int out_size, void* d_ws, size_t ws_size,
                              hipStream_t stream) {
  const float* x  = (const float*)d_in[0];
  const float* wq = (const float*)d_in[1];
  const float* wk = (const float*)d_in[2];
  const float* wv = (const float*)d_in[3];
  const float* wo = (const float*)d_in[4];
  const float* fc = (const float*)d_in[5];
  const float* fs = (const float*)d_in[6];

  float* out = (float*)d_out;
  float* nck = out + 9437184;      // 4*2048*1152
  float* ncv = nck + 1835008;      // 4*1792*4*64

  char* ws = (char*)d_ws;
  u16* attnb = (u16*)(ws);                    // attn out bf16 [8192][1024]
  u16* wqkvb = (u16*)(ws + 18874368);         // wq|wk|wv bf16 [1536][1152]
  u16* wob   = (u16*)(ws + 22413312);         // wo bf16       [1152][1024]
  u16* qkv   = (u16*)(ws + 24772608);         // qkv bf16      [8192][1536]
  u16* vT    = (u16*)(ws + 49938432);         // v^T bf16 (virtual-k permuted)

  cvt3_kernel<<<1728, 256, 0, stream>>>(wq, wk, wv, wqkvb);

  // QKV GEMM reads x fp32 directly; A reg-staged with T14 issue-early.
  gemm_bt<1, 1><<<768, 256, 0, stream>>>(x, wqkvb, qkv, 8192, 1536, 1152, 12);

  ropev_kernel<<<5760, 256, 0, stream>>>(qkv, nck, vT, ncv, wo, wob, fc, fs);

  attn_kernel<<<1024, 256, 0, stream>>>(qkv, vT, attnb, fc, fs);

  gemm_bt<0, 0><<<576, 256, 0, stream>>>(attnb, wob, out, 8192, 1152, 1024, 9);
}